// Round 8
// baseline (340.391 us; speedup 1.0000x reference)
//
#include <hip/hip_runtime.h>
#include <hip/hip_bf16.h>
#include <math.h>

constexpr int kD  = 1024;
constexpr int kB  = 2;
constexpr int kL  = 2048;
constexpr int kM  = kB * kL; // 4096 rows total

typedef __attribute__((ext_vector_type(8))) short  bf8v;   // 8 bf16 (4 VGPR) MFMA frag
typedef __attribute__((ext_vector_type(4))) float  f4v;    // MFMA accumulator
typedef __attribute__((ext_vector_type(4))) unsigned short us4v;

#define MFMA_BF16 __builtin_amdgcn_mfma_f32_16x16x32_bf16

__device__ inline unsigned short f2bf(float f) {
    __hip_bfloat16 h = __float2bfloat16(f);
    return *(unsigned short*)&h;
}
__device__ inline float bf2f(unsigned short u) {
    __hip_bfloat16 h = *(__hip_bfloat16*)&u;
    return __bfloat162float(h);
}
// async global->LDS, 16B per lane; lds dest = wave-uniform base + lane*16
__device__ inline void gload16(const void* g, void* l) {
    __builtin_amdgcn_global_load_lds(
        (const __attribute__((address_space(1))) void*)g,
        (__attribute__((address_space(3))) void*)l, 16, 0, 0);
}

// ---------------- split-convert: fp32 -> (hi, lo) bf16 ----------------
__global__ __launch_bounds__(256) void convert_split(
    const float* __restrict__ src, unsigned short* __restrict__ hi,
    unsigned short* __restrict__ lo, int n4)
{
    const int i = blockIdx.x * 256 + threadIdx.x;
    if (i >= n4) return;
    const float4 v = ((const float4*)src)[i];
    const float vv[4] = {v.x, v.y, v.z, v.w};
    us4v h, l;
    #pragma unroll
    for (int c = 0; c < 4; ++c) {
        h[c] = f2bf(vv[c]);
        l[c] = f2bf(vv[c] - bf2f(h[c]));
    }
    *(us4v*)&hi[(size_t)i * 4] = h;
    *(us4v*)&lo[(size_t)i * 4] = l;
}

// ---------------- LayerNorm -> split bf16 ----------------
__global__ __launch_bounds__(256) void ln_kernel(
    const float* __restrict__ x, const float* __restrict__ g,
    const float* __restrict__ beta, unsigned short* __restrict__ h_hi,
    unsigned short* __restrict__ h_lo)
{
    const int row = blockIdx.x;
    const int tid = threadIdx.x;
    const float4 v = ((const float4*)(x + (size_t)row * kD))[tid];
    float s  = v.x + v.y + v.z + v.w;
    float s2 = v.x*v.x + v.y*v.y + v.z*v.z + v.w*v.w;
    #pragma unroll
    for (int off = 32; off > 0; off >>= 1) {
        s  += __shfl_down(s, off);
        s2 += __shfl_down(s2, off);
    }
    __shared__ float wsum[4], wsum2[4];
    const int lane = tid & 63, wid = tid >> 6;
    if (lane == 0) { wsum[wid] = s; wsum2[wid] = s2; }
    __syncthreads();
    const float ts   = wsum[0] + wsum[1] + wsum[2] + wsum[3];
    const float ts2  = wsum2[0] + wsum2[1] + wsum2[2] + wsum2[3];
    const float mean = ts * (1.0f / kD);
    const float var  = ts2 * (1.0f / kD) - mean * mean;
    const float rstd = rsqrtf(var + 1e-5f);
    const float4 gv = ((const float4*)g)[tid];
    const float4 bv = ((const float4*)beta)[tid];
    float o[4];
    o[0] = (v.x - mean) * rstd * gv.x + bv.x;
    o[1] = (v.y - mean) * rstd * gv.y + bv.y;
    o[2] = (v.z - mean) * rstd * gv.z + bv.z;
    o[3] = (v.w - mean) * rstd * gv.w + bv.w;
    us4v h, l;
    #pragma unroll
    for (int c = 0; c < 4; ++c) {
        h[c] = f2bf(o[c]);
        l[c] = f2bf(o[c] - bf2f(h[c]));
    }
    *(us4v*)&h_hi[(size_t)row * kD + tid * 4] = h;
    *(us4v*)&h_lo[(size_t)row * kD + tid * 4] = l;
}

// ---------------- split-bf16 MFMA NT GEMM, global_load_lds, BK=64 ----------
// MODE 0 (QKV): acc = AhBh + AhBl + AlBh; out bf16: Q cols prescaled 1/32 ->
//               projb (cols<2048), V cols transposed -> vT[b*16+h][64][2048].
// MODE 1 (WO):  acc = AhBh + AhBl (A single); out fp32 = gelu(resid+acc+bias).
// LDS [128][64] linear per array; swizzle: LDS[row][c] = global[row][c^(row&7)]
// (source pre-swizzled, same XOR on read; dest stays linear for gload_lds).
template<int MODE>
__global__ __launch_bounds__(256, (MODE == 0) ? 2 : 3) void gemm_split(
    const unsigned short* __restrict__ Ahi, const unsigned short* __restrict__ Alo,
    const unsigned short* __restrict__ Bhi, const unsigned short* __restrict__ Blo,
    const float* __restrict__ bias, const float* __restrict__ resid,
    unsigned short* __restrict__ outb, unsigned short* __restrict__ vT,
    float* __restrict__ outf, int N, int K)
{
    constexpr int NARR = (MODE == 0) ? 4 : 3;
    __shared__ unsigned short S[NARR][128][64];   // MODE0: 64KB, MODE1: 48KB
    const int tid = threadIdx.x;
    const int l = tid & 63, w = tid >> 6;
    const int col16 = l & 15, grp = l >> 4;
    const int wr = (w >> 1) * 64, wc = (w & 1) * 64;
    const int row0 = blockIdx.y * 128, col0 = blockIdx.x * 128;
    // staging geometry: gload t covers 8 rows x 64 cols (1KB);
    // lane -> (row t*8 + l>>3, chunk l&7); source chunk = (l&7)^(l>>3)
    const int sr8 = l >> 3;
    const int sc8 = ((l & 7) ^ sr8) * 8;
    const unsigned short* gb;
    int rb;
    if (MODE == 0) {
        gb = (w == 0) ? Ahi : (w == 1) ? Alo : (w == 2) ? Bhi : Blo;
        rb = (w < 2) ? row0 : col0;
    } else {
        gb = (w == 0) ? Ahi : (w == 1) ? Bhi : Blo;
        rb = (w == 0) ? row0 : col0;
    }
    const bool do_stage = (MODE == 0) || (w < 3);
    const int sw7 = col16 & 7;                  // read-side swizzle key (= row&7)
    f4v acc[4][4] = {};

    for (int k0 = 0; k0 < K; k0 += 64) {
        __syncthreads();
        if (do_stage) {
            #pragma unroll
            for (int t = 0; t < 16; ++t)
                gload16(gb + (size_t)(rb + t*8 + sr8) * K + k0 + sc8,
                        &S[w][t*8][0]);
        }
        __syncthreads();   // compiler drains vmcnt(0) here
        #pragma unroll
        for (int kk = 0; kk < 2; ++kk) {
            const int pos8 = ((grp + kk*4) ^ sw7) * 8;
            bf8v ah[4], al[4], bh[4], bl[4];
            #pragma unroll
            for (int mi = 0; mi < 4; ++mi) {
                ah[mi] = *(bf8v*)&S[0][wr + mi*16 + col16][pos8];
                if (MODE == 0) al[mi] = *(bf8v*)&S[1][wr + mi*16 + col16][pos8];
            }
            #pragma unroll
            for (int ni = 0; ni < 4; ++ni) {
                bh[ni] = *(bf8v*)&S[(MODE == 0) ? 2 : 1][wc + ni*16 + col16][pos8];
                bl[ni] = *(bf8v*)&S[(MODE == 0) ? 3 : 2][wc + ni*16 + col16][pos8];
            }
            #pragma unroll
            for (int mi = 0; mi < 4; ++mi)
                #pragma unroll
                for (int ni = 0; ni < 4; ++ni) {
                    acc[mi][ni] = MFMA_BF16(ah[mi], bh[ni], acc[mi][ni], 0, 0, 0);
                    acc[mi][ni] = MFMA_BF16(ah[mi], bl[ni], acc[mi][ni], 0, 0, 0);
                    if (MODE == 0)
                        acc[mi][ni] = MFMA_BF16(al[mi], bh[ni], acc[mi][ni], 0, 0, 0);
                }
        }
    }
    #pragma unroll
    for (int mi = 0; mi < 4; ++mi)
        #pragma unroll
        for (int ni = 0; ni < 4; ++ni) {
            const int gcol = col0 + wc + ni*16 + col16;
            const float bb = bias[gcol];
            #pragma unroll
            for (int rr = 0; rr < 4; ++rr) {
                const int grow = row0 + wr + mi*16 + grp*4 + rr;
                float o = acc[mi][ni][rr] + bb;
                if (MODE == 0) {
                    if (gcol < 2048) {
                        if (gcol < 1024) o *= (1.0f / 32.0f);  // fold softmax scale into Q
                        outb[(size_t)grow * 3072 + gcol] = f2bf(o);
                    } else {
                        const int dg = gcol - 2048;
                        vT[((size_t)((grow >> 11) * 16 + (dg >> 6)) * 64 + (dg & 63)) * 2048
                           + (grow & 2047)] = f2bf(o);
                    }
                } else {
                    o += resid[(size_t)grow * N + gcol];
                    o = 0.5f * o * (1.0f + erff(o * 0.70710678118654752f));
                    outf[(size_t)grow * N + gcol] = o;
                }
            }
        }
}

// ---------------- MFMA flash attention v4: 8 waves, QBLK=128 ----------------
// K from projb, V from pre-transposed vT; staged via global_load_lds into
// linear [64][64] LDS with chunk swizzle. Q in registers (prescaled).
// Each K/V tile + barrier pair now serves 128 q-rows. 51.2KB LDS -> 3 blk/CU.
__global__ __launch_bounds__(512, 6) void attn_mfma(
    const unsigned short* __restrict__ projb, const unsigned short* __restrict__ vT,
    unsigned short* __restrict__ heads_hi)
{
    __shared__ unsigned short Ks[64 * 64];
    __shared__ unsigned short Vs[64 * 64];
    __shared__ unsigned int   Ps32[8][16][68];  // (hi | lo<<16) packed P
    const int tid = threadIdx.x;
    const int l = tid & 63, w = tid >> 6;       // 8 waves; wave owns 16 q-rows
    const int col16 = l & 15, grp = l >> 4;
    const int bh = blockIdx.x, b = bh >> 4, hh = bh & 15;
    const int qt = 15 - (int)blockIdx.y;        // big tiles dispatch first
    const int q0 = qt * 128;
    const unsigned short* vTh = vT + (size_t)bh * 64 * 2048;

    // staging: 16 gloads of 1KB (8 rows x 64 cols); waves 0-3 -> K, 4-7 -> V
    const int r8 = l >> 3;
    const int sc8 = ((l & 7) ^ r8) * 8;         // swizzled source col
    const bool isV = w >= 4;
    const int tA = (w & 3) * 2;                 // this wave's two 8-row groups
    const int sw7 = col16 & 7;                  // read-side swizzle key

    // Q A-frags straight from global (already 1/32-prescaled by GEMM epilogue)
    const size_t qbase = (size_t)(b*kL + q0 + w*16 + col16) * 3072 + hh*64 + grp*8;
    bf8v aq[2];
    aq[0] = *(const bf8v*)&projb[qbase];
    aq[1] = *(const bf8v*)&projb[qbase + 32];

    f4v accO[4] = {};
    float m_r[4], l_r[4];
    #pragma unroll
    for (int r = 0; r < 4; ++r) { m_r[r] = -INFINITY; l_r[r] = 0.0f; }

    const int ntiles = 2 * qt + 2;
    for (int jt = 0; jt < ntiles; ++jt) {
        const int j0 = jt * 64;
        __syncthreads();   // prev tile's reads done before DMA overwrites
        #pragma unroll
        for (int t2 = 0; t2 < 2; ++t2) {
            const int t = tA + t2;
            if (isV)
                gload16(&vTh[(size_t)(t*8 + r8) * 2048 + j0 + sc8], &Vs[t*8*64]);
            else
                gload16(&projb[(size_t)(b*kL + j0 + t*8 + r8) * 3072 + hh*64 + 1024 + sc8],
                        &Ks[t*8*64]);
        }
        __syncthreads();   // vmcnt(0) drain -> tiles ready

        // waves 0-3 are fully masked on the block's final (upper-diag) tile
        if (!((jt == 2*qt + 1) && (w < 4))) {
            // S = (Q/32) K^T
            f4v accS[4] = {};
            #pragma unroll
            for (int kk = 0; kk < 2; ++kk)
                #pragma unroll
                for (int nj = 0; nj < 4; ++nj) {
                    const int row = nj*16 + col16;
                    const bf8v bk = *(bf8v*)&Ks[row*64 + (((grp + kk*4) ^ sw7) * 8)];
                    accS[nj] = MFMA_BF16(aq[kk], bk, accS[nj], 0, 0, 0);
                }

            // causal mask (uniform): mask when (jt-2qt)*64 + j_local > q_local
            const int joff = (jt - 2*qt) * 64;
            float p[4][4];  // [nj][r]
            float alpha[4];
            #pragma unroll
            for (int r = 0; r < 4; ++r) {
                const int qloc = w*16 + grp*4 + r;
                float sv[4];
                #pragma unroll
                for (int nj = 0; nj < 4; ++nj) {
                    sv[nj] = accS[nj][r];
                    if (joff + nj*16 + col16 > qloc) sv[nj] = -1e9f;
                }
                float pm = fmaxf(fmaxf(sv[0], sv[1]), fmaxf(sv[2], sv[3]));
                pm = fmaxf(pm, __shfl_xor(pm, 1));
                pm = fmaxf(pm, __shfl_xor(pm, 2));
                pm = fmaxf(pm, __shfl_xor(pm, 4));
                pm = fmaxf(pm, __shfl_xor(pm, 8));
                const float m_new = fmaxf(m_r[r], pm);
                alpha[r] = __expf(m_r[r] - m_new);
                m_r[r] = m_new;
                float ps = 0.0f;
                #pragma unroll
                for (int nj = 0; nj < 4; ++nj) {
                    p[nj][r] = __expf(sv[nj] - m_new);
                    ps += p[nj][r];
                }
                ps += __shfl_xor(ps, 1);
                ps += __shfl_xor(ps, 2);
                ps += __shfl_xor(ps, 4);
                ps += __shfl_xor(ps, 8);
                l_r[r] = l_r[r] * alpha[r] + ps;
            }
            #pragma unroll
            for (int nd = 0; nd < 4; ++nd)
                #pragma unroll
                for (int r = 0; r < 4; ++r)
                    accO[nd][r] *= alpha[r];

            // P -> LDS, hi|lo packed u32 (wave-private slab, conflict-free)
            #pragma unroll
            for (int nj = 0; nj < 4; ++nj)
                #pragma unroll
                for (int r = 0; r < 4; ++r) {
                    const unsigned hi = f2bf(p[nj][r]);
                    const unsigned lo = f2bf(p[nj][r] - bf2f((unsigned short)hi));
                    Ps32[w][grp*4 + r][nj*16 + col16] = hi | (lo << 16);
                }
            asm volatile("s_waitcnt lgkmcnt(0)" ::: "memory"); // wave DS in order

            // O += (Phi + Plo) V
            #pragma unroll
            for (int js = 0; js < 2; ++js) {
                const uint4 pa0 = *(const uint4*)&Ps32[w][col16][js*32 + grp*8];
                const uint4 pa1 = *(const uint4*)&Ps32[w][col16][js*32 + grp*8 + 4];
                const unsigned pu[8] = {pa0.x, pa0.y, pa0.z, pa0.w,
                                        pa1.x, pa1.y, pa1.z, pa1.w};
                bf8v ph, pl;
                #pragma unroll
                for (int i = 0; i < 8; ++i) {
                    ph[i] = (short)(pu[i] & 0xffffu);
                    pl[i] = (short)(pu[i] >> 16);
                }
                #pragma unroll
                for (int nd = 0; nd < 4; ++nd) {
                    const int row = nd*16 + col16;
                    const bf8v bv = *(bf8v*)&Vs[row*64 + (((grp + js*4) ^ sw7) * 8)];
                    accO[nd] = MFMA_BF16(ph, bv, accO[nd], 0, 0, 0);
                    accO[nd] = MFMA_BF16(pl, bv, accO[nd], 0, 0, 0);
                }
            }
        }
    }
    // epilogue: heads bf16 (single round; lo-term dropped in WO GEMM)
    #pragma unroll
    for (int nd = 0; nd < 4; ++nd)
        #pragma unroll
        for (int r = 0; r < 4; ++r) {
            const float o = accO[nd][r] / l_r[r];
            heads_hi[(size_t)(b*kL + q0 + w*16 + grp*4 + r) * kD
                     + hh*64 + nd*16 + col16] = f2bf(o);
        }
}

extern "C" void kernel_launch(void* const* d_in, const int* in_sizes, int n_in,
                              void* d_out, int out_size, void* d_ws, size_t ws_size,
                              hipStream_t stream)
{
    const float* x    = (const float*)d_in[0];
    const float* mask = (const float*)d_in[1];
    const float* wx_w = (const float*)d_in[2];
    const float* wx_b = (const float*)d_in[3];
    const float* wo_w = (const float*)d_in[4];
    const float* wo_b = (const float*)d_in[5];
    const float* ln_g = (const float*)d_in[6];
    const float* ln_b = (const float*)d_in[7];
    float* out = (float*)d_out;

    // ws (ushort elems): h_hi 4M | h_lo 4M | wxhi 3M | wxlo 3M | wohi 1M | wolo 1M
    //                    | projb 12M | hd_hi 4M | vT 4M   = 36M elems = 72MB
    unsigned short* h_hi  = (unsigned short*)d_ws;
    unsigned short* h_lo  = h_hi  + (size_t)kM * kD;
    unsigned short* wxhi  = h_lo  + (size_t)kM * kD;
    unsigned short* wxlo  = wxhi  + (size_t)3 * kD * kD;
    unsigned short* wohi  = wxlo  + (size_t)3 * kD * kD;
    unsigned short* wolo  = wohi  + (size_t)kD * kD;
    unsigned short* projb = wolo  + (size_t)kD * kD;
    unsigned short* hd_hi = projb + (size_t)kM * 3 * kD;
    unsigned short* vT    = hd_hi + (size_t)kM * kD;

    convert_split<<<(3*kD*kD/4 + 255)/256, 256, 0, stream>>>(wx_w, wxhi, wxlo, 3*kD*kD/4);
    convert_split<<<(kD*kD/4 + 255)/256, 256, 0, stream>>>(wo_w, wohi, wolo, kD*kD/4);
    ln_kernel<<<kM, 256, 0, stream>>>(x, ln_g, ln_b, h_hi, h_lo);
    gemm_split<0><<<dim3(3*kD/128, kM/128), 256, 0, stream>>>(
        h_hi, h_lo, wxhi, wxlo, wx_b, nullptr, projb, vT, nullptr, 3*kD, kD);
    attn_mfma<<<dim3(kB*16, kL/128), 512, 0, stream>>>(projb, vT, hd_hi);
    gemm_split<1><<<dim3(kD/128, kM/128), 256, 0, stream>>>(
        hd_hi, nullptr, wohi, wolo, wo_b, x, nullptr, nullptr, out, kD, kD);
    hipMemcpyAsync(out + (size_t)kM * kD, mask, (size_t)kL * kL * sizeof(float),
                   hipMemcpyDeviceToDevice, stream);
}

// Round 9
// 294.691 us; speedup vs baseline: 1.1551x; 1.1551x over previous
//
#include <hip/hip_runtime.h>
#include <hip/hip_bf16.h>
#include <math.h>

constexpr int kD  = 1024;
constexpr int kB  = 2;
constexpr int kL  = 2048;
constexpr int kM  = kB * kL; // 4096 rows total

typedef __attribute__((ext_vector_type(8))) short  bf8v;   // 8 bf16 (4 VGPR) MFMA frag
typedef __attribute__((ext_vector_type(4))) float  f4v;    // MFMA accumulator
typedef __attribute__((ext_vector_type(4))) unsigned short us4v;

#define MFMA_BF16 __builtin_amdgcn_mfma_f32_16x16x32_bf16

__device__ inline unsigned short f2bf(float f) {
    __hip_bfloat16 h = __float2bfloat16(f);
    return *(unsigned short*)&h;
}
__device__ inline float bf2f(unsigned short u) {
    __hip_bfloat16 h = *(__hip_bfloat16*)&u;
    return __bfloat162float(h);
}
// async global->LDS, 16B per lane; lds dest = wave-uniform base + lane*16
__device__ inline void gload16(const void* g, void* l) {
    __builtin_amdgcn_global_load_lds(
        (const __attribute__((address_space(1))) void*)g,
        (__attribute__((address_space(3))) void*)l, 16, 0, 0);
}

// ---------------- split-convert: fp32 -> (hi, lo) bf16 ----------------
__global__ __launch_bounds__(256) void convert_split(
    const float* __restrict__ src, unsigned short* __restrict__ hi,
    unsigned short* __restrict__ lo, int n4)
{
    const int i = blockIdx.x * 256 + threadIdx.x;
    if (i >= n4) return;
    const float4 v = ((const float4*)src)[i];
    const float vv[4] = {v.x, v.y, v.z, v.w};
    us4v h, l;
    #pragma unroll
    for (int c = 0; c < 4; ++c) {
        h[c] = f2bf(vv[c]);
        l[c] = f2bf(vv[c] - bf2f(h[c]));
    }
    *(us4v*)&hi[(size_t)i * 4] = h;
    *(us4v*)&lo[(size_t)i * 4] = l;
}

// ---------------- LayerNorm -> bf16 (hi only; lo term dropped in QKV) -------
__global__ __launch_bounds__(256) void ln_kernel(
    const float* __restrict__ x, const float* __restrict__ g,
    const float* __restrict__ beta, unsigned short* __restrict__ h_hi)
{
    const int row = blockIdx.x;
    const int tid = threadIdx.x;
    const float4 v = ((const float4*)(x + (size_t)row * kD))[tid];
    float s  = v.x + v.y + v.z + v.w;
    float s2 = v.x*v.x + v.y*v.y + v.z*v.z + v.w*v.w;
    #pragma unroll
    for (int off = 32; off > 0; off >>= 1) {
        s  += __shfl_down(s, off);
        s2 += __shfl_down(s2, off);
    }
    __shared__ float wsum[4], wsum2[4];
    const int lane = tid & 63, wid = tid >> 6;
    if (lane == 0) { wsum[wid] = s; wsum2[wid] = s2; }
    __syncthreads();
    const float ts   = wsum[0] + wsum[1] + wsum[2] + wsum[3];
    const float ts2  = wsum2[0] + wsum2[1] + wsum2[2] + wsum2[3];
    const float mean = ts * (1.0f / kD);
    const float var  = ts2 * (1.0f / kD) - mean * mean;
    const float rstd = rsqrtf(var + 1e-5f);
    const float4 gv = ((const float4*)g)[tid];
    const float4 bv = ((const float4*)beta)[tid];
    float o[4];
    o[0] = (v.x - mean) * rstd * gv.x + bv.x;
    o[1] = (v.y - mean) * rstd * gv.y + bv.y;
    o[2] = (v.z - mean) * rstd * gv.z + bv.z;
    o[3] = (v.w - mean) * rstd * gv.w + bv.w;
    us4v h;
    #pragma unroll
    for (int c = 0; c < 4; ++c) h[c] = f2bf(o[c]);
    *(us4v*)&h_hi[(size_t)row * kD + tid * 4] = h;
}

// ---------------- 2-term split bf16 MFMA NT GEMM, global_load_lds, BK=32 ----
// C = A[M,K] * (Bhi+Blo)[N,K]^T  (acc = A·Bh + A·Bl).
// MODE 0 (QKV): out bf16: Q cols prescaled 1/32 -> projb (cols<2048),
//               V cols transposed -> vT[b*16+h][64][2048].
// MODE 1 (WO):  out fp32 = gelu(resid + acc + bias).
// LDS [128][32] linear x3 = 24KB; swizzle LDS[r][c]=global[r][c^((r>>1)&3)]
// (pre-swizzled source + same XOR on read; dest linear for gload_lds).
// B-frags loaded per-ni to keep live regs low (occupancy is unified-VGPR-bound).
template<int MODE>
__global__ __launch_bounds__(256, 3) void gemm_split(
    const unsigned short* __restrict__ A,
    const unsigned short* __restrict__ Bhi, const unsigned short* __restrict__ Blo,
    const float* __restrict__ bias, const float* __restrict__ resid,
    unsigned short* __restrict__ outb, unsigned short* __restrict__ vT,
    float* __restrict__ outf, int N, int K)
{
    __shared__ unsigned short S[3][128][32];
    const int tid = threadIdx.x;
    const int l = tid & 63, w = tid >> 6;
    const int col16 = l & 15, grp = l >> 4;
    const int wr = (w >> 1) * 64, wc = (w & 1) * 64;
    const int row0 = blockIdx.y * 128, col0 = blockIdx.x * 128;
    // staging: gload t covers 16 rows x 32 cols (1KB);
    // lane -> (row t*16 + l>>2, chunk l&3); source chunk = (l&3)^((row>>1)&3)
    const int sr = l >> 2;
    const int sc8 = ((l & 3) ^ ((sr >> 1) & 3)) * 8;
    const unsigned short* gb = (w == 0) ? A : (w == 1) ? Bhi : Blo;
    const int rb = (w == 0) ? row0 : col0;
    const int pos8 = (grp ^ ((col16 >> 1) & 3)) * 8;   // read-side swizzle
    f4v acc[4][4] = {};

    for (int k0 = 0; k0 < K; k0 += 32) {
        __syncthreads();
        if (w < 3) {
            #pragma unroll
            for (int t = 0; t < 8; ++t)
                gload16(gb + (size_t)(rb + t*16 + sr) * K + k0 + sc8,
                        &S[w][t*16][0]);
        }
        __syncthreads();   // compiler drains vmcnt(0) here
        bf8v ah[4];
        #pragma unroll
        for (int mi = 0; mi < 4; ++mi)
            ah[mi] = *(bf8v*)&S[0][wr + mi*16 + col16][pos8];
        #pragma unroll
        for (int ni = 0; ni < 4; ++ni) {
            const bf8v bh = *(bf8v*)&S[1][wc + ni*16 + col16][pos8];
            const bf8v bl = *(bf8v*)&S[2][wc + ni*16 + col16][pos8];
            #pragma unroll
            for (int mi = 0; mi < 4; ++mi) {
                acc[mi][ni] = MFMA_BF16(ah[mi], bh, acc[mi][ni], 0, 0, 0);
                acc[mi][ni] = MFMA_BF16(ah[mi], bl, acc[mi][ni], 0, 0, 0);
            }
        }
    }
    #pragma unroll
    for (int mi = 0; mi < 4; ++mi)
        #pragma unroll
        for (int ni = 0; ni < 4; ++ni) {
            const int gcol = col0 + wc + ni*16 + col16;
            const float bb = bias[gcol];
            #pragma unroll
            for (int rr = 0; rr < 4; ++rr) {
                const int grow = row0 + wr + mi*16 + grp*4 + rr;
                float o = acc[mi][ni][rr] + bb;
                if (MODE == 0) {
                    if (gcol < 2048) {
                        if (gcol < 1024) o *= (1.0f / 32.0f);  // fold softmax scale into Q
                        outb[(size_t)grow * 3072 + gcol] = f2bf(o);
                    } else {
                        const int dg = gcol - 2048;
                        vT[((size_t)((grow >> 11) * 16 + (dg >> 6)) * 64 + (dg & 63)) * 2048
                           + (grow & 2047)] = f2bf(o);
                    }
                } else {
                    o += resid[(size_t)grow * N + gcol];
                    o = 0.5f * o * (1.0f + erff(o * 0.70710678118654752f));
                    outf[(size_t)grow * N + gcol] = o;
                }
            }
        }
}

// ---------------- MFMA flash attention (R6 config: QBLK=64, 4 waves) --------
// K from projb, V from pre-transposed vT; staged via global_load_lds into
// linear [64][64] LDS with chunk swizzle. Q in registers (prescaled).
__global__ __launch_bounds__(256, 4) void attn_mfma(
    const unsigned short* __restrict__ projb, const unsigned short* __restrict__ vT,
    unsigned short* __restrict__ heads_hi)
{
    __shared__ unsigned short Ks[64 * 64];
    __shared__ unsigned short Vs[64 * 64];
    __shared__ unsigned int   Ps32[4][16][68];  // (hi | lo<<16) packed P
    const int tid = threadIdx.x;
    const int l = tid & 63, w = tid >> 6;
    const int col16 = l & 15, grp = l >> 4;
    const int bh = blockIdx.x, b = bh >> 4, hh = bh & 15;
    const int qt = 31 - (int)blockIdx.y;      // big tiles dispatch first
    const int q0 = qt * 64;
    const unsigned short* vTh = vT + (size_t)bh * 64 * 2048;

    // staging lane geometry: 1KB per gload = 8 rows x 64 cols
    const int r8 = l >> 3;
    const int sc8 = ((l & 7) ^ r8) * 8;       // swizzled source col
    const int isV = w >> 1;
    const int t0 = (w & 1) * 4;
    const int sw7 = col16 & 7;                 // read-side swizzle key

    // Q A-frags straight from global (already 1/32-prescaled by GEMM epilogue)
    const size_t qbase = (size_t)(b*kL + q0 + w*16 + col16) * 3072 + hh*64 + grp*8;
    bf8v aq[2];
    aq[0] = *(const bf8v*)&projb[qbase];
    aq[1] = *(const bf8v*)&projb[qbase + 32];

    f4v accO[4] = {};
    float m_r[4], l_r[4];
    #pragma unroll
    for (int r = 0; r < 4; ++r) { m_r[r] = -INFINITY; l_r[r] = 0.0f; }

    for (int jt = 0; jt <= qt; ++jt) {
        const int j0 = jt * 64;
        __syncthreads();   // prev tile's reads done before DMA overwrites
        #pragma unroll
        for (int t2 = 0; t2 < 4; ++t2) {
            const int t = t0 + t2;
            if (isV)
                gload16(&vTh[(size_t)(t*8 + r8) * 2048 + j0 + sc8], &Vs[t*8*64]);
            else
                gload16(&projb[(size_t)(b*kL + j0 + t*8 + r8) * 3072 + hh*64 + 1024 + sc8],
                        &Ks[t*8*64]);
        }
        __syncthreads();   // vmcnt(0) drain -> tiles ready

        // S = (Q/32) K^T
        f4v accS[4] = {};
        #pragma unroll
        for (int kk = 0; kk < 2; ++kk)
            #pragma unroll
            for (int nj = 0; nj < 4; ++nj) {
                const int row = nj*16 + col16;
                const bf8v bk = *(bf8v*)&Ks[row*64 + (((grp + kk*4) ^ sw7) * 8)];
                accS[nj] = MFMA_BF16(aq[kk], bk, accS[nj], 0, 0, 0);
            }

        // causal mask + wave-private online softmax
        const bool diag = (jt == qt);
        float p[4][4];  // [nj][r]
        float alpha[4];
        #pragma unroll
        for (int r = 0; r < 4; ++r) {
            const int q_local = w*16 + grp*4 + r;
            float sv[4];
            #pragma unroll
            for (int nj = 0; nj < 4; ++nj) {
                sv[nj] = accS[nj][r];
                if (diag && (nj*16 + col16 > q_local)) sv[nj] = -1e9f;
            }
            float pm = fmaxf(fmaxf(sv[0], sv[1]), fmaxf(sv[2], sv[3]));
            pm = fmaxf(pm, __shfl_xor(pm, 1));
            pm = fmaxf(pm, __shfl_xor(pm, 2));
            pm = fmaxf(pm, __shfl_xor(pm, 4));
            pm = fmaxf(pm, __shfl_xor(pm, 8));
            const float m_new = fmaxf(m_r[r], pm);
            alpha[r] = __expf(m_r[r] - m_new);
            m_r[r] = m_new;
            float ps = 0.0f;
            #pragma unroll
            for (int nj = 0; nj < 4; ++nj) {
                p[nj][r] = __expf(sv[nj] - m_new);
                ps += p[nj][r];
            }
            ps += __shfl_xor(ps, 1);
            ps += __shfl_xor(ps, 2);
            ps += __shfl_xor(ps, 4);
            ps += __shfl_xor(ps, 8);
            l_r[r] = l_r[r] * alpha[r] + ps;
        }
        #pragma unroll
        for (int nd = 0; nd < 4; ++nd)
            #pragma unroll
            for (int r = 0; r < 4; ++r)
                accO[nd][r] *= alpha[r];

        // P -> LDS, hi|lo packed u32 (conflict-free)
        #pragma unroll
        for (int nj = 0; nj < 4; ++nj)
            #pragma unroll
            for (int r = 0; r < 4; ++r) {
                const unsigned hi = f2bf(p[nj][r]);
                const unsigned lo = f2bf(p[nj][r] - bf2f((unsigned short)hi));
                Ps32[w][grp*4 + r][nj*16 + col16] = hi | (lo << 16);
            }
        asm volatile("s_waitcnt lgkmcnt(0)" ::: "memory"); // wave DS ops in order

        // O += (Phi + Plo) V
        #pragma unroll
        for (int js = 0; js < 2; ++js) {
            const uint4 pa0 = *(const uint4*)&Ps32[w][col16][js*32 + grp*8];
            const uint4 pa1 = *(const uint4*)&Ps32[w][col16][js*32 + grp*8 + 4];
            const unsigned pu[8] = {pa0.x, pa0.y, pa0.z, pa0.w,
                                    pa1.x, pa1.y, pa1.z, pa1.w};
            bf8v ph, pl;
            #pragma unroll
            for (int i = 0; i < 8; ++i) {
                ph[i] = (short)(pu[i] & 0xffffu);
                pl[i] = (short)(pu[i] >> 16);
            }
            #pragma unroll
            for (int nd = 0; nd < 4; ++nd) {
                const int row = nd*16 + col16;
                const bf8v bv = *(bf8v*)&Vs[row*64 + (((grp + js*4) ^ sw7) * 8)];
                accO[nd] = MFMA_BF16(ph, bv, accO[nd], 0, 0, 0);
                accO[nd] = MFMA_BF16(pl, bv, accO[nd], 0, 0, 0);
            }
        }
    }
    // epilogue: heads bf16 (single round; lo-term dropped in WO GEMM)
    #pragma unroll
    for (int nd = 0; nd < 4; ++nd)
        #pragma unroll
        for (int r = 0; r < 4; ++r) {
            const float o = accO[nd][r] / l_r[r];
            heads_hi[(size_t)(b*kL + q0 + w*16 + grp*4 + r) * kD
                     + hh*64 + nd*16 + col16] = f2bf(o);
        }
}

extern "C" void kernel_launch(void* const* d_in, const int* in_sizes, int n_in,
                              void* d_out, int out_size, void* d_ws, size_t ws_size,
                              hipStream_t stream)
{
    const float* x    = (const float*)d_in[0];
    const float* mask = (const float*)d_in[1];
    const float* wx_w = (const float*)d_in[2];
    const float* wx_b = (const float*)d_in[3];
    const float* wo_w = (const float*)d_in[4];
    const float* wo_b = (const float*)d_in[5];
    const float* ln_g = (const float*)d_in[6];
    const float* ln_b = (const float*)d_in[7];
    float* out = (float*)d_out;

    // ws (ushort elems): h_hi 4M | spare 4M | wxhi 3M | wxlo 3M | wohi 1M | wolo 1M
    //                    | projb 12M | hd_hi 4M | vT 4M   = 36M elems = 72MB
    unsigned short* h_hi  = (unsigned short*)d_ws;
    unsigned short* h_lo  = h_hi  + (size_t)kM * kD;  // unused (kept for layout)
    unsigned short* wxhi  = h_lo  + (size_t)kM * kD;
    unsigned short* wxlo  = wxhi  + (size_t)3 * kD * kD;
    unsigned short* wohi  = wxlo  + (size_t)3 * kD * kD;
    unsigned short* wolo  = wohi  + (size_t)kD * kD;
    unsigned short* projb = wolo  + (size_t)kD * kD;
    unsigned short* hd_hi = projb + (size_t)kM * 3 * kD;
    unsigned short* vT    = hd_hi + (size_t)kM * kD;

    convert_split<<<(3*kD*kD/4 + 255)/256, 256, 0, stream>>>(wx_w, wxhi, wxlo, 3*kD*kD/4);
    convert_split<<<(kD*kD/4 + 255)/256, 256, 0, stream>>>(wo_w, wohi, wolo, kD*kD/4);
    ln_kernel<<<kM, 256, 0, stream>>>(x, ln_g, ln_b, h_hi);
    gemm_split<0><<<dim3(3*kD/128, kM/128), 256, 0, stream>>>(
        h_hi, wxhi, wxlo, wx_b, nullptr, projb, vT, nullptr, 3*kD, kD);
    attn_mfma<<<dim3(kB*16, kL/64), 256, 0, stream>>>(projb, vT, hd_hi);
    gemm_split<1><<<dim3(kD/128, kM/128), 256, 0, stream>>>(
        hd_hi, wohi, wolo, wo_b, x, nullptr, nullptr, out, kD, kD);
    hipMemcpyAsync(out + (size_t)kM * kD, mask, (size_t)kL * kL * sizeof(float),
                   hipMemcpyDeviceToDevice, stream);
}

// Round 11
// 277.128 us; speedup vs baseline: 1.2283x; 1.0634x over previous
//
#include <hip/hip_runtime.h>
#include <hip/hip_bf16.h>
#include <math.h>

constexpr int kD  = 1024;
constexpr int kB  = 2;
constexpr int kL  = 2048;
constexpr int kM  = kB * kL; // 4096 rows total

typedef __attribute__((ext_vector_type(8))) short  bf8v;   // 8 bf16 (4 VGPR) MFMA frag
typedef __attribute__((ext_vector_type(4))) float  f4v;    // MFMA accumulator
typedef __attribute__((ext_vector_type(4))) unsigned short us4v;

#define MFMA_BF16 __builtin_amdgcn_mfma_f32_16x16x32_bf16

__device__ inline unsigned short f2bf(float f) {
    __hip_bfloat16 h = __float2bfloat16(f);
    return *(unsigned short*)&h;
}
__device__ inline float bf2f(unsigned short u) {
    __hip_bfloat16 h = *(__hip_bfloat16*)&u;
    return __bfloat162float(h);
}
// async global->LDS, 16B per lane; lds dest = wave-uniform base + lane*16
__device__ inline void gload16(const void* g, void* l) {
    __builtin_amdgcn_global_load_lds(
        (const __attribute__((address_space(1))) void*)g,
        (__attribute__((address_space(3))) void*)l, 16, 0, 0);
}

// ---------------- split-convert: fp32 -> (hi, lo) bf16 ----------------
__global__ __launch_bounds__(256) void convert_split(
    const float* __restrict__ src, unsigned short* __restrict__ hi,
    unsigned short* __restrict__ lo, int n4)
{
    const int i = blockIdx.x * 256 + threadIdx.x;
    if (i >= n4) return;
    const float4 v = ((const float4*)src)[i];
    const float vv[4] = {v.x, v.y, v.z, v.w};
    us4v h, l;
    #pragma unroll
    for (int c = 0; c < 4; ++c) {
        h[c] = f2bf(vv[c]);
        l[c] = f2bf(vv[c] - bf2f(h[c]));
    }
    *(us4v*)&hi[(size_t)i * 4] = h;
    *(us4v*)&lo[(size_t)i * 4] = l;
}

// ---------------- LayerNorm -> bf16 (hi only; lo term dropped in QKV) -------
__global__ __launch_bounds__(256) void ln_kernel(
    const float* __restrict__ x, const float* __restrict__ g,
    const float* __restrict__ beta, unsigned short* __restrict__ h_hi)
{
    const int row = blockIdx.x;
    const int tid = threadIdx.x;
    const float4 v = ((const float4*)(x + (size_t)row * kD))[tid];
    float s  = v.x + v.y + v.z + v.w;
    float s2 = v.x*v.x + v.y*v.y + v.z*v.z + v.w*v.w;
    #pragma unroll
    for (int off = 32; off > 0; off >>= 1) {
        s  += __shfl_down(s, off);
        s2 += __shfl_down(s2, off);
    }
    __shared__ float wsum[4], wsum2[4];
    const int lane = tid & 63, wid = tid >> 6;
    if (lane == 0) { wsum[wid] = s; wsum2[wid] = s2; }
    __syncthreads();
    const float ts   = wsum[0] + wsum[1] + wsum[2] + wsum[3];
    const float ts2  = wsum2[0] + wsum2[1] + wsum2[2] + wsum2[3];
    const float mean = ts * (1.0f / kD);
    const float var  = ts2 * (1.0f / kD) - mean * mean;
    const float rstd = rsqrtf(var + 1e-5f);
    const float4 gv = ((const float4*)g)[tid];
    const float4 bv = ((const float4*)beta)[tid];
    float o[4];
    o[0] = (v.x - mean) * rstd * gv.x + bv.x;
    o[1] = (v.y - mean) * rstd * gv.y + bv.y;
    o[2] = (v.z - mean) * rstd * gv.z + bv.z;
    o[3] = (v.w - mean) * rstd * gv.w + bv.w;
    us4v h;
    #pragma unroll
    for (int c = 0; c < 4; ++c) h[c] = f2bf(o[c]);
    *(us4v*)&h_hi[(size_t)row * kD + tid * 4] = h;
}

// ---------------- 2-term split bf16 MFMA NT GEMM, 2-phase prefetch ----------
// C = A[M,K] * (Bhi+Blo)[N,K]^T.  Double-buffered LDS, ONE barrier per K-step:
//   prologue STAGE(buf0,k=0); loop { barrier(drain); STAGE(buf^1,k+32); MFMA(buf); }
// MODE 0 (QKV): out bf16: Q cols prescaled 1/32 -> projb, V -> vT transposed.
// MODE 1 (WO):  out fp32 = gelu(resid + acc + bias).
// Swizzle LDS[r][c]=global[r][c^((r>>1)&3)] (source pre-swizzle + same XOR read).
template<int MODE>
__global__ __launch_bounds__(256, 3) void gemm_split(
    const unsigned short* __restrict__ A,
    const unsigned short* __restrict__ Bhi, const unsigned short* __restrict__ Blo,
    const float* __restrict__ bias, const float* __restrict__ resid,
    unsigned short* __restrict__ outb, unsigned short* __restrict__ vT,
    float* __restrict__ outf, int N, int K)
{
    __shared__ unsigned short S[2][3][128][32];   // 48KB -> 3 blocks/CU
    const int tid = threadIdx.x;
    const int l = tid & 63, w = tid >> 6;
    const int col16 = l & 15, grp = l >> 4;
    const int wr = (w >> 1) * 64, wc = (w & 1) * 64;
    const int row0 = blockIdx.y * 128, col0 = blockIdx.x * 128;
    // staging: gload t covers 16 rows x 32 cols (1KB); lane -> (row t*16 + l>>2,
    // chunk l&3); source chunk = (l&3)^((row>>1)&3)
    const int sr = l >> 2;
    const int sc8 = ((l & 3) ^ ((sr >> 1) & 3)) * 8;
    const unsigned short* gb = (w == 0) ? A : (w == 1) ? Bhi : Blo;
    const int rb = (w == 0) ? row0 : col0;
    const int pos8 = (grp ^ ((col16 >> 1) & 3)) * 8;   // read-side swizzle
    f4v acc[4][4] = {};

    auto stage = [&](int buf, int k0s) {
        #pragma unroll
        for (int t = 0; t < 8; ++t)
            gload16(gb + (size_t)(rb + t*16 + sr) * K + k0s + sc8,
                    &S[buf][w][t*16][0]);
    };
    if (w < 3) stage(0, 0);
    int cur = 0;
    for (int k0 = 0; k0 < K; k0 += 32) {
        __syncthreads();   // drains this wave's gloads -> S[cur] ready; also
                           // all waves done reading S[cur^1] from prev iter
        if (w < 3 && k0 + 32 < K) stage(cur ^ 1, k0 + 32);
        bf8v ah[4];
        #pragma unroll
        for (int mi = 0; mi < 4; ++mi)
            ah[mi] = *(bf8v*)&S[cur][0][wr + mi*16 + col16][pos8];
        #pragma unroll
        for (int ni = 0; ni < 4; ++ni) {
            const bf8v bh = *(bf8v*)&S[cur][1][wc + ni*16 + col16][pos8];
            const bf8v bl = *(bf8v*)&S[cur][2][wc + ni*16 + col16][pos8];
            #pragma unroll
            for (int mi = 0; mi < 4; ++mi) {
                acc[mi][ni] = MFMA_BF16(ah[mi], bh, acc[mi][ni], 0, 0, 0);
                acc[mi][ni] = MFMA_BF16(ah[mi], bl, acc[mi][ni], 0, 0, 0);
            }
        }
        cur ^= 1;
    }
    #pragma unroll
    for (int mi = 0; mi < 4; ++mi)
        #pragma unroll
        for (int ni = 0; ni < 4; ++ni) {
            const int gcol = col0 + wc + ni*16 + col16;
            const float bb = bias[gcol];
            #pragma unroll
            for (int rr = 0; rr < 4; ++rr) {
                const int grow = row0 + wr + mi*16 + grp*4 + rr;
                float o = acc[mi][ni][rr] + bb;
                if (MODE == 0) {
                    if (gcol < 2048) {
                        if (gcol < 1024) o *= (1.0f / 32.0f);  // fold softmax scale into Q
                        outb[(size_t)grow * 3072 + gcol] = f2bf(o);
                    } else {
                        const int dg = gcol - 2048;
                        vT[((size_t)((grow >> 11) * 16 + (dg >> 6)) * 64 + (dg & 63)) * 2048
                           + (grow & 2047)] = f2bf(o);
                    }
                } else {
                    o += resid[(size_t)grow * N + gcol];
                    o = 0.5f * o * (1.0f + erff(o * 0.70710678118654752f));
                    outf[(size_t)grow * N + gcol] = o;
                }
            }
        }
}

// ---------------- MFMA flash attention v5 ----------------
// QBLK=64, 4 waves. Double-buffered K/V with 2-phase prefetch (one barrier/tile).
// P single bf16 (lo dropped). Exact defer-max: skip rescale when max unchanged.
__global__ __launch_bounds__(256, 3) void attn_mfma(
    const unsigned short* __restrict__ projb, const unsigned short* __restrict__ vT,
    unsigned short* __restrict__ heads_hi)
{
    __shared__ unsigned short Ks[2][64 * 64];
    __shared__ unsigned short Vs[2][64 * 64];
    __shared__ unsigned int   Ps32[4][16][68];  // P (bf16, zero-extended u32)
    const int tid = threadIdx.x;
    const int l = tid & 63, w = tid >> 6;
    const int col16 = l & 15, grp = l >> 4;
    const int bh = blockIdx.x, b = bh >> 4, hh = bh & 15;
    const int qt = 31 - (int)blockIdx.y;      // big tiles dispatch first
    const int q0 = qt * 64;
    const unsigned short* vTh = vT + (size_t)bh * 64 * 2048;

    // staging lane geometry: 1KB per gload = 8 rows x 64 cols
    const int r8 = l >> 3;
    const int sc8 = ((l & 7) ^ r8) * 8;       // swizzled source col
    const int isV = w >> 1;
    const int t0 = (w & 1) * 4;
    const int sw7 = col16 & 7;                 // read-side swizzle key

    // Q A-frags straight from global (already 1/32-prescaled by GEMM epilogue)
    const size_t qbase = (size_t)(b*kL + q0 + w*16 + col16) * 3072 + hh*64 + grp*8;
    bf8v aq[2];
    aq[0] = *(const bf8v*)&projb[qbase];
    aq[1] = *(const bf8v*)&projb[qbase + 32];

    f4v accO[4] = {};
    float m_r[4], l_r[4];
    #pragma unroll
    for (int r = 0; r < 4; ++r) { m_r[r] = -INFINITY; l_r[r] = 0.0f; }

    auto stage = [&](int buf, int j0s) {
        #pragma unroll
        for (int t2 = 0; t2 < 4; ++t2) {
            const int t = t0 + t2;
            if (isV)
                gload16(&vTh[(size_t)(t*8 + r8) * 2048 + j0s + sc8],
                        &Vs[buf][t*8*64]);
            else
                gload16(&projb[(size_t)(b*kL + j0s + t*8 + r8) * 3072 + hh*64 + 1024 + sc8],
                        &Ks[buf][t*8*64]);
        }
    };
    stage(0, 0);
    int cur = 0;
    for (int jt = 0; jt <= qt; ++jt) {
        __syncthreads();   // drains gloads -> buf[cur] ready; prev reads done
        if (jt < qt) stage(cur ^ 1, (jt + 1) * 64);

        // S = (Q/32) K^T
        f4v accS[4] = {};
        #pragma unroll
        for (int kk = 0; kk < 2; ++kk)
            #pragma unroll
            for (int nj = 0; nj < 4; ++nj) {
                const int row = nj*16 + col16;
                const bf8v bk = *(bf8v*)&Ks[cur][row*64 + (((grp + kk*4) ^ sw7) * 8)];
                accS[nj] = MFMA_BF16(aq[kk], bk, accS[nj], 0, 0, 0);
            }

        // causal mask + row max
        const bool diag = (jt == qt);
        float sv[4][4], pm[4];
        #pragma unroll
        for (int r = 0; r < 4; ++r) {
            const int q_local = w*16 + grp*4 + r;
            #pragma unroll
            for (int nj = 0; nj < 4; ++nj) {
                sv[r][nj] = accS[nj][r];
                if (diag && (nj*16 + col16 > q_local)) sv[r][nj] = -1e9f;
            }
            float p = fmaxf(fmaxf(sv[r][0], sv[r][1]), fmaxf(sv[r][2], sv[r][3]));
            p = fmaxf(p, __shfl_xor(p, 1));
            p = fmaxf(p, __shfl_xor(p, 2));
            p = fmaxf(p, __shfl_xor(p, 4));
            p = fmaxf(p, __shfl_xor(p, 8));
            pm[r] = p;
        }
        // exact defer-max: rescale only if any row max grew (wave-uniform branch)
        const bool grow = (pm[0] > m_r[0]) || (pm[1] > m_r[1]) ||
                          (pm[2] > m_r[2]) || (pm[3] > m_r[3]);
        if (__any(grow)) {
            #pragma unroll
            for (int r = 0; r < 4; ++r) {
                const float m_new = fmaxf(m_r[r], pm[r]);
                const float al = __expf(m_r[r] - m_new);
                m_r[r] = m_new;
                l_r[r] *= al;
                #pragma unroll
                for (int nd = 0; nd < 4; ++nd) accO[nd][r] *= al;
            }
        }
        // P = exp(S - m), row-sum into l
        float p[4][4];  // [nj][r]
        #pragma unroll
        for (int r = 0; r < 4; ++r) {
            float ps = 0.0f;
            #pragma unroll
            for (int nj = 0; nj < 4; ++nj) {
                p[nj][r] = __expf(sv[r][nj] - m_r[r]);
                ps += p[nj][r];
            }
            ps += __shfl_xor(ps, 1);
            ps += __shfl_xor(ps, 2);
            ps += __shfl_xor(ps, 4);
            ps += __shfl_xor(ps, 8);
            l_r[r] += ps;
        }
        // P -> LDS (bf16 zero-extended u32, conflict-light)
        #pragma unroll
        for (int nj = 0; nj < 4; ++nj)
            #pragma unroll
            for (int r = 0; r < 4; ++r)
                Ps32[w][grp*4 + r][nj*16 + col16] = (unsigned)f2bf(p[nj][r]);
        asm volatile("s_waitcnt lgkmcnt(0)" ::: "memory"); // wave DS ops in order

        // O += P V
        #pragma unroll
        for (int js = 0; js < 2; ++js) {
            const uint4 pa0 = *(const uint4*)&Ps32[w][col16][js*32 + grp*8];
            const uint4 pa1 = *(const uint4*)&Ps32[w][col16][js*32 + grp*8 + 4];
            const unsigned pu[8] = {pa0.x, pa0.y, pa0.z, pa0.w,
                                    pa1.x, pa1.y, pa1.z, pa1.w};
            bf8v ph;
            #pragma unroll
            for (int i = 0; i < 8; ++i) ph[i] = (short)(pu[i] & 0xffffu);
            #pragma unroll
            for (int nd = 0; nd < 4; ++nd) {
                const int row = nd*16 + col16;
                const bf8v bv = *(bf8v*)&Vs[cur][row*64 + (((grp + js*4) ^ sw7) * 8)];
                accO[nd] = MFMA_BF16(ph, bv, accO[nd], 0, 0, 0);
            }
        }
        cur ^= 1;
    }
    // epilogue: heads bf16
    #pragma unroll
    for (int nd = 0; nd < 4; ++nd)
        #pragma unroll
        for (int r = 0; r < 4; ++r) {
            const float o = accO[nd][r] / l_r[r];
            heads_hi[(size_t)(b*kL + q0 + w*16 + grp*4 + r) * kD
                     + hh*64 + nd*16 + col16] = f2bf(o);
        }
}

extern "C" void kernel_launch(void* const* d_in, const int* in_sizes, int n_in,
                              void* d_out, int out_size, void* d_ws, size_t ws_size,
                              hipStream_t stream)
{
    const float* x    = (const float*)d_in[0];
    const float* mask = (const float*)d_in[1];
    const float* wx_w = (const float*)d_in[2];
    const float* wx_b = (const float*)d_in[3];
    const float* wo_w = (const float*)d_in[4];
    const float* wo_b = (const float*)d_in[5];
    const float* ln_g = (const float*)d_in[6];
    const float* ln_b = (const float*)d_in[7];
    float* out = (float*)d_out;

    // ws (ushort elems): h_hi 4M | spare 4M | wxhi 3M | wxlo 3M | wohi 1M | wolo 1M
    //                    | projb 12M | hd_hi 4M | vT 4M   = 36M elems = 72MB
    unsigned short* h_hi  = (unsigned short*)d_ws;
    unsigned short* h_lo  = h_hi  + (size_t)kM * kD;  // unused (kept for layout)
    unsigned short* wxhi  = h_lo  + (size_t)kM * kD;
    unsigned short* wxlo  = wxhi  + (size_t)3 * kD * kD;
    unsigned short* wohi  = wxlo  + (size_t)3 * kD * kD;
    unsigned short* wolo  = wohi  + (size_t)kD * kD;
    unsigned short* projb = wolo  + (size_t)kD * kD;
    unsigned short* hd_hi = projb + (size_t)kM * 3 * kD;
    unsigned short* vT    = hd_hi + (size_t)kM * kD;

    convert_split<<<(3*kD*kD/4 + 255)/256, 256, 0, stream>>>(wx_w, wxhi, wxlo, 3*kD*kD/4);
    convert_split<<<(kD*kD/4 + 255)/256, 256, 0, stream>>>(wo_w, wohi, wolo, kD*kD/4);
    ln_kernel<<<kM, 256, 0, stream>>>(x, ln_g, ln_b, h_hi);
    gemm_split<0><<<dim3(3*kD/128, kM/128), 256, 0, stream>>>(
        h_hi, wxhi, wxlo, wx_b, nullptr, projb, vT, nullptr, 3*kD, kD);
    attn_mfma<<<dim3(kB*16, kL/64), 256, 0, stream>>>(projb, vT, hd_hi);
    gemm_split<1><<<dim3(kD/128, kM/128), 256, 0, stream>>>(
        hd_hi, wohi, wolo, wo_b, x, nullptr, nullptr, out, kD, kD);
    hipMemcpyAsync(out + (size_t)kM * kD, mask, (size_t)kL * kL * sizeof(float),
                   hipMemcpyDeviceToDevice, stream);
}